// Round 2
// baseline (795.135 us; speedup 1.0000x reference)
//
#include <hip/hip_runtime.h>

#define KVOX 12000
#define TPTS 35
#define FIN  7
#define DD   10
#define HH   400
#define WW   352
#define CO   128
#define EPSBN 1e-3f
#define NCELL (DD * HH * WW)          // 1,408,000 cells
#define CELLS_PER_BLK 8               // gather kernel: 32 lanes per cell

// ---------------- compute voxelwise features + push into per-cell list ----------------
__global__ __launch_bounds__(64) void vfe_compute(
    const float* __restrict__ feat,
    const float* __restrict__ w1, const float* __restrict__ b1,
    const float* __restrict__ g1, const float* __restrict__ be1,
    const float* __restrict__ m1, const float* __restrict__ v1,
    const float* __restrict__ w2, const float* __restrict__ b2,
    const float* __restrict__ g2, const float* __restrict__ be2,
    const float* __restrict__ m2, const float* __restrict__ v2,
    const int* __restrict__ coord,
    float* __restrict__ vox,          // [KVOX, 128]
    int* __restrict__ head,           // [NCELL], pre-init -1
    int* __restrict__ nxt)            // [KVOX]
{
    const int k   = blockIdx.x;
    const int tid = threadIdx.x;

    __shared__ float sx[TPTS][FIN];
    __shared__ float smask[TPTS];
    __shared__ __align__(16) float sx2[TPTS][32];

    const float* fk = feat + (size_t)k * (TPTS * FIN);
    for (int i = tid; i < TPTS * FIN; i += 64)
        ((float*)sx)[i] = fk[i];
    __syncthreads();

    bool pred = false;
    if (tid < TPTS) {
        float mx = sx[tid][0];
        #pragma unroll
        for (int f = 1; f < FIN; ++f) mx = fmaxf(mx, sx[tid][f]);
        pred = (mx != 0.0f);
        smask[tid] = pred ? 1.0f : 0.0f;
    }
    unsigned long long bal = __ballot(pred);
    const int nvalid = __popcll(bal);
    __syncthreads();

    // stage 1: dense(7->16)+relu+BN; agg over ALL t; masked concat -> sx2[t][0..31]
    if (tid < 16) {
        const int u = tid;
        float w1c[FIN];
        #pragma unroll
        for (int f = 0; f < FIN; ++f) w1c[f] = w1[f * 16 + u];
        const float b     = b1[u];
        const float scale = g1[u] * rsqrtf(v1[u] + EPSBN);
        const float shift = be1[u] - m1[u] * scale;

        float agg = -INFINITY;
        float pw[TPTS];
        #pragma unroll
        for (int t = 0; t < TPTS; ++t) {
            float d = b;
            #pragma unroll
            for (int f = 0; f < FIN; ++f) d = fmaf(sx[t][f], w1c[f], d);
            d = fmaxf(d, 0.0f);
            float p = fmaf(d, scale, shift);
            agg = fmaxf(agg, p);
            pw[t] = p;
        }
        #pragma unroll
        for (int t = 0; t < TPTS; ++t) {
            const float mk = smask[t];
            sx2[t][u]      = pw[t] * mk;
            sx2[t][16 + u] = agg   * mk;
        }
    }
    __syncthreads();

    // stage 2: dense(32->64)+relu+BN, channel per lane; voxelwise max
    {
        const int v = tid;
        float w2c[32];
        #pragma unroll
        for (int u = 0; u < 32; ++u) w2c[u] = w2[u * 64 + v];
        const float b     = b2[v];
        const float scale = g2[v] * rsqrtf(v2[v] + EPSBN);
        const float shift = be2[v] - m2[v] * scale;

        float aggAll = -INFINITY;
        float voxA   = -INFINITY;
        #pragma unroll 5
        for (int t = 0; t < TPTS; ++t) {
            float d = b;
            const float4* xr = (const float4*)(&sx2[t][0]);
            #pragma unroll
            for (int q = 0; q < 8; ++q) {
                float4 xv = xr[q];   // same-address LDS broadcast
                d = fmaf(xv.x, w2c[4 * q + 0], d);
                d = fmaf(xv.y, w2c[4 * q + 1], d);
                d = fmaf(xv.z, w2c[4 * q + 2], d);
                d = fmaf(xv.w, w2c[4 * q + 3], d);
            }
            d = fmaxf(d, 0.0f);
            float p = fmaf(d, scale, shift);
            aggAll = fmaxf(aggAll, p);
            voxA   = fmaxf(voxA, p * smask[t]);
        }
        float voxB;
        if (nvalid == 0)          voxB = 0.0f;
        else if (nvalid < TPTS)   voxB = fmaxf(aggAll, 0.0f);
        else                      voxB = aggAll;

        float* vk = vox + (size_t)k * CO;
        vk[v]      = voxA;
        vk[64 + v] = voxB;

        if (v == 0) {
            const int4 c = ((const int4*)coord)[k];
            const int loc = (((c.x * DD + c.y) * HH + c.z) * WW + c.w);
            nxt[k] = atomicExch(&head[loc], k);   // push k onto cell list
        }
    }
}

// ---------------- single output pass: zero + gather-accumulate ----------------
__global__ __launch_bounds__(256) void gather_out(
    const float* __restrict__ vox, const int* __restrict__ head,
    const int* __restrict__ nxt, float* __restrict__ out)
{
    const int tid  = threadIdx.x;
    const int cell = blockIdx.x * CELLS_PER_BLK + (tid >> 5);
    const int lane = tid & 31;

    float4 acc = make_float4(0.f, 0.f, 0.f, 0.f);
    int s = head[cell];                 // uniform within the 32-lane group
    while (s >= 0) {
        const float4 v = ((const float4*)vox)[s * 32 + lane];
        acc.x += v.x; acc.y += v.y; acc.z += v.z; acc.w += v.w;
        s = nxt[s];
    }
    ((float4*)out)[(size_t)cell * 32 + lane] = acc;  // 1KB contiguous per wave
}

// ---------------- fallback (R1 path) if ws is too small ----------------
__global__ __launch_bounds__(64) void vfe_scatter_atomic(
    const float* __restrict__ feat,
    const float* __restrict__ w1, const float* __restrict__ b1,
    const float* __restrict__ g1, const float* __restrict__ be1,
    const float* __restrict__ m1, const float* __restrict__ v1,
    const float* __restrict__ w2, const float* __restrict__ b2,
    const float* __restrict__ g2, const float* __restrict__ be2,
    const float* __restrict__ m2, const float* __restrict__ v2,
    const int* __restrict__ coord,
    float* __restrict__ out)
{
    const int k   = blockIdx.x;
    const int tid = threadIdx.x;
    __shared__ float sx[TPTS][FIN];
    __shared__ float smask[TPTS];
    __shared__ __align__(16) float sx2[TPTS][32];
    const float* fk = feat + (size_t)k * (TPTS * FIN);
    for (int i = tid; i < TPTS * FIN; i += 64) ((float*)sx)[i] = fk[i];
    __syncthreads();
    bool pred = false;
    if (tid < TPTS) {
        float mx = sx[tid][0];
        #pragma unroll
        for (int f = 1; f < FIN; ++f) mx = fmaxf(mx, sx[tid][f]);
        pred = (mx != 0.0f);
        smask[tid] = pred ? 1.0f : 0.0f;
    }
    unsigned long long bal = __ballot(pred);
    const int nvalid = __popcll(bal);
    __syncthreads();
    if (tid < 16) {
        const int u = tid;
        float w1c[FIN];
        #pragma unroll
        for (int f = 0; f < FIN; ++f) w1c[f] = w1[f * 16 + u];
        const float b = b1[u];
        const float scale = g1[u] * rsqrtf(v1[u] + EPSBN);
        const float shift = be1[u] - m1[u] * scale;
        float agg = -INFINITY;
        float pw[TPTS];
        #pragma unroll
        for (int t = 0; t < TPTS; ++t) {
            float d = b;
            #pragma unroll
            for (int f = 0; f < FIN; ++f) d = fmaf(sx[t][f], w1c[f], d);
            d = fmaxf(d, 0.0f);
            float p = fmaf(d, scale, shift);
            agg = fmaxf(agg, p);
            pw[t] = p;
        }
        #pragma unroll
        for (int t = 0; t < TPTS; ++t) {
            const float mk = smask[t];
            sx2[t][u] = pw[t] * mk;
            sx2[t][16 + u] = agg * mk;
        }
    }
    __syncthreads();
    {
        const int v = tid;
        float w2c[32];
        #pragma unroll
        for (int u = 0; u < 32; ++u) w2c[u] = w2[u * 64 + v];
        const float b = b2[v];
        const float scale = g2[v] * rsqrtf(v2[v] + EPSBN);
        const float shift = be2[v] - m2[v] * scale;
        float aggAll = -INFINITY, voxA = -INFINITY;
        #pragma unroll 5
        for (int t = 0; t < TPTS; ++t) {
            float d = b;
            const float4* xr = (const float4*)(&sx2[t][0]);
            #pragma unroll
            for (int q = 0; q < 8; ++q) {
                float4 xv = xr[q];
                d = fmaf(xv.x, w2c[4 * q + 0], d);
                d = fmaf(xv.y, w2c[4 * q + 1], d);
                d = fmaf(xv.z, w2c[4 * q + 2], d);
                d = fmaf(xv.w, w2c[4 * q + 3], d);
            }
            d = fmaxf(d, 0.0f);
            float p = fmaf(d, scale, shift);
            aggAll = fmaxf(aggAll, p);
            voxA = fmaxf(voxA, p * smask[t]);
        }
        float voxB;
        if (nvalid == 0) voxB = 0.0f;
        else if (nvalid < TPTS) voxB = fmaxf(aggAll, 0.0f);
        else voxB = aggAll;
        const int4 c = ((const int4*)coord)[k];
        const int loc = (((c.x * DD + c.y) * HH + c.z) * WW + c.w);
        float* o = out + (size_t)loc * CO;
        atomicAdd(o + v, voxA);
        atomicAdd(o + 64 + v, voxB);
    }
}

extern "C" void kernel_launch(void* const* d_in, const int* in_sizes, int n_in,
                              void* d_out, int out_size, void* d_ws, size_t ws_size,
                              hipStream_t stream) {
    const float* feat = (const float*)d_in[0];
    const float* w1   = (const float*)d_in[1];
    const float* b1   = (const float*)d_in[2];
    const float* g1   = (const float*)d_in[3];
    const float* be1  = (const float*)d_in[4];
    const float* m1   = (const float*)d_in[5];
    const float* v1   = (const float*)d_in[6];
    const float* w2   = (const float*)d_in[7];
    const float* b2   = (const float*)d_in[8];
    const float* g2   = (const float*)d_in[9];
    const float* be2  = (const float*)d_in[10];
    const float* m2   = (const float*)d_in[11];
    const float* v2   = (const float*)d_in[12];
    const int*   coord = (const int*)d_in[13];
    float* out = (float*)d_out;

    // ws layout: vox [KVOX*CO f32] | head [NCELL i32] | nxt [KVOX i32]
    const size_t voxB  = (size_t)KVOX * CO * sizeof(float);     // 6,144,000
    const size_t headB = (size_t)NCELL * sizeof(int);           // 5,632,000
    const size_t nxtB  = (size_t)KVOX * sizeof(int);            //    48,000
    const size_t need  = voxB + headB + nxtB;

    if (ws_size >= need) {
        float* vox = (float*)d_ws;
        int*   head = (int*)((char*)d_ws + voxB);
        int*   nxt  = (int*)((char*)d_ws + voxB + headB);

        hipMemsetAsync(head, 0xFF, headB, stream);              // head = -1
        vfe_compute<<<KVOX, 64, 0, stream>>>(feat, w1, b1, g1, be1, m1, v1,
                                             w2, b2, g2, be2, m2, v2, coord,
                                             vox, head, nxt);
        gather_out<<<NCELL / CELLS_PER_BLK, 256, 0, stream>>>(vox, head, nxt, out);
    } else {
        hipMemsetAsync(d_out, 0, (size_t)out_size * sizeof(float), stream);
        vfe_scatter_atomic<<<KVOX, 64, 0, stream>>>(feat, w1, b1, g1, be1, m1, v1,
                                                    w2, b2, g2, be2, m2, v2, coord, out);
    }
}

// Round 3
// 757.267 us; speedup vs baseline: 1.0500x; 1.0500x over previous
//
#include <hip/hip_runtime.h>

#define KVOX 12000
#define TPTS 35
#define FIN  7
#define DD   10
#define HH   400
#define WW   352
#define CO   128
#define EPSBN 1e-3f
#define NCELL (DD * HH * WW)              // 1,408,000 cells
#define CB    3000                        // fused kernel blocks (4 waves = 4 voxels each)
#define TOTALF4 ((size_t)NCELL * 32)      // 45,056,000 float4s = 720.9 MB
#define SB    1500                        // scatter kernel blocks

// ---- fused: zero-fill `out` + compute voxelwise [KVOX,128] into ws ----
// Independent jobs fused so the store pipe (fill) and VALU/LDS (compute)
// overlap. Block parity alternates phase order so stores saturate from t=0.
__global__ __launch_bounds__(256) void fused_fill_compute(
    const float* __restrict__ feat,
    const float* __restrict__ w1, const float* __restrict__ b1,
    const float* __restrict__ g1, const float* __restrict__ be1,
    const float* __restrict__ m1, const float* __restrict__ v1,
    const float* __restrict__ w2, const float* __restrict__ b2,
    const float* __restrict__ g2, const float* __restrict__ be2,
    const float* __restrict__ m2, const float* __restrict__ v2,
    float* __restrict__ vox,          // [KVOX, 128]
    float* __restrict__ out)
{
    const int tid  = threadIdx.x;
    const int wv   = tid >> 6;        // wave in block: 0..3
    const int lane = tid & 63;
    const int k    = blockIdx.x * 4 + wv;   // CB*4 == KVOX exactly

    __shared__ float sx[4][TPTS][FIN];
    __shared__ float smask[4][TPTS];
    __shared__ __align__(16) float sx2[4][TPTS][32];

    const bool fillFirst = (blockIdx.x & 1);

    // ---------------- fill phase (zero out), grid-stride float4 ----------------
    auto do_fill = [&]() {
        const float4 z = make_float4(0.f, 0.f, 0.f, 0.f);
        float4* o4 = (float4*)out;
        const size_t stride = (size_t)CB * 256;
        for (size_t i = (size_t)blockIdx.x * 256 + tid; i < TOTALF4; i += stride)
            o4[i] = z;
    };

    if (fillFirst) do_fill();

    // ---------------- compute phase: one wave per voxel ----------------
    {
        const float* fk = feat + (size_t)k * (TPTS * FIN);
        for (int i = lane; i < TPTS * FIN; i += 64)
            ((float*)sx[wv])[i] = fk[i];
        __syncthreads();

        bool pred = false;
        if (lane < TPTS) {
            float mx = sx[wv][lane][0];
            #pragma unroll
            for (int f = 1; f < FIN; ++f) mx = fmaxf(mx, sx[wv][lane][f]);
            pred = (mx != 0.0f);
            smask[wv][lane] = pred ? 1.0f : 0.0f;
        }
        unsigned long long bal = __ballot(pred);
        const int nvalid = __popcll(bal);
        __syncthreads();

        // stage 1: dense(7->16)+relu+BN; agg over ALL t; masked concat
        if (lane < 16) {
            const int u = lane;
            float w1c[FIN];
            #pragma unroll
            for (int f = 0; f < FIN; ++f) w1c[f] = w1[f * 16 + u];
            const float b     = b1[u];
            const float scale = g1[u] * rsqrtf(v1[u] + EPSBN);
            const float shift = be1[u] - m1[u] * scale;

            float agg = -INFINITY;
            float pw[TPTS];
            #pragma unroll
            for (int t = 0; t < TPTS; ++t) {
                float d = b;
                #pragma unroll
                for (int f = 0; f < FIN; ++f) d = fmaf(sx[wv][t][f], w1c[f], d);
                d = fmaxf(d, 0.0f);
                float p = fmaf(d, scale, shift);
                agg = fmaxf(agg, p);
                pw[t] = p;
            }
            #pragma unroll
            for (int t = 0; t < TPTS; ++t) {
                const float mk = smask[wv][t];
                sx2[wv][t][u]      = pw[t] * mk;
                sx2[wv][t][16 + u] = agg   * mk;
            }
        }
        __syncthreads();

        // stage 2: dense(32->64)+relu+BN, channel per lane; voxelwise max
        {
            const int v = lane;
            float w2c[32];
            #pragma unroll
            for (int u = 0; u < 32; ++u) w2c[u] = w2[u * 64 + v];
            const float b     = b2[v];
            const float scale = g2[v] * rsqrtf(v2[v] + EPSBN);
            const float shift = be2[v] - m2[v] * scale;

            float aggAll = -INFINITY;
            float voxA   = -INFINITY;
            #pragma unroll 5
            for (int t = 0; t < TPTS; ++t) {
                float d = b;
                const float4* xr = (const float4*)(&sx2[wv][t][0]);
                #pragma unroll
                for (int q = 0; q < 8; ++q) {
                    float4 xv = xr[q];   // same-address LDS broadcast
                    d = fmaf(xv.x, w2c[4 * q + 0], d);
                    d = fmaf(xv.y, w2c[4 * q + 1], d);
                    d = fmaf(xv.z, w2c[4 * q + 2], d);
                    d = fmaf(xv.w, w2c[4 * q + 3], d);
                }
                d = fmaxf(d, 0.0f);
                float p = fmaf(d, scale, shift);
                aggAll = fmaxf(aggAll, p);
                voxA   = fmaxf(voxA, p * smask[wv][t]);
            }
            float voxB;
            if (nvalid == 0)          voxB = 0.0f;
            else if (nvalid < TPTS)   voxB = fmaxf(aggAll, 0.0f);
            else                      voxB = aggAll;

            float* vk = vox + (size_t)k * CO;
            vk[v]      = voxA;
            vk[64 + v] = voxB;
        }
    }

    if (!fillFirst) do_fill();
}

// ---- tiny scatter: out[cell(k)*128 + ch] += vox[k*128 + ch] (dups accumulate) ----
__global__ __launch_bounds__(256) void scatter_add(
    const float* __restrict__ vox, const int* __restrict__ coord,
    float* __restrict__ out)
{
    const int stride = SB * 256;
    for (int i = blockIdx.x * 256 + threadIdx.x; i < KVOX * CO; i += stride) {
        const int k  = i >> 7;
        const int ch = i & (CO - 1);
        const int4 c = ((const int4*)coord)[k];   // 128 lanes share k -> L1 broadcast
        const int loc = (((c.x * DD + c.y) * HH + c.z) * WW + c.w);
        atomicAdd(out + (size_t)loc * CO + ch, vox[i]);
    }
}

// ---- fallback (R1 path) if ws is too small ----
__global__ __launch_bounds__(64) void vfe_scatter_atomic(
    const float* __restrict__ feat,
    const float* __restrict__ w1, const float* __restrict__ b1,
    const float* __restrict__ g1, const float* __restrict__ be1,
    const float* __restrict__ m1, const float* __restrict__ v1,
    const float* __restrict__ w2, const float* __restrict__ b2,
    const float* __restrict__ g2, const float* __restrict__ be2,
    const float* __restrict__ m2, const float* __restrict__ v2,
    const int* __restrict__ coord,
    float* __restrict__ out)
{
    const int k   = blockIdx.x;
    const int tid = threadIdx.x;
    __shared__ float sx[TPTS][FIN];
    __shared__ float smask[TPTS];
    __shared__ __align__(16) float sx2[TPTS][32];
    const float* fk = feat + (size_t)k * (TPTS * FIN);
    for (int i = tid; i < TPTS * FIN; i += 64) ((float*)sx)[i] = fk[i];
    __syncthreads();
    bool pred = false;
    if (tid < TPTS) {
        float mx = sx[tid][0];
        #pragma unroll
        for (int f = 1; f < FIN; ++f) mx = fmaxf(mx, sx[tid][f]);
        pred = (mx != 0.0f);
        smask[tid] = pred ? 1.0f : 0.0f;
    }
    unsigned long long bal = __ballot(pred);
    const int nvalid = __popcll(bal);
    __syncthreads();
    if (tid < 16) {
        const int u = tid;
        float w1c[FIN];
        #pragma unroll
        for (int f = 0; f < FIN; ++f) w1c[f] = w1[f * 16 + u];
        const float b = b1[u];
        const float scale = g1[u] * rsqrtf(v1[u] + EPSBN);
        const float shift = be1[u] - m1[u] * scale;
        float agg = -INFINITY;
        float pw[TPTS];
        #pragma unroll
        for (int t = 0; t < TPTS; ++t) {
            float d = b;
            #pragma unroll
            for (int f = 0; f < FIN; ++f) d = fmaf(sx[t][f], w1c[f], d);
            d = fmaxf(d, 0.0f);
            float p = fmaf(d, scale, shift);
            agg = fmaxf(agg, p);
            pw[t] = p;
        }
        #pragma unroll
        for (int t = 0; t < TPTS; ++t) {
            const float mk = smask[t];
            sx2[t][u] = pw[t] * mk;
            sx2[t][16 + u] = agg * mk;
        }
    }
    __syncthreads();
    {
        const int v = tid;
        float w2c[32];
        #pragma unroll
        for (int u = 0; u < 32; ++u) w2c[u] = w2[u * 64 + v];
        const float b = b2[v];
        const float scale = g2[v] * rsqrtf(v2[v] + EPSBN);
        const float shift = be2[v] - m2[v] * scale;
        float aggAll = -INFINITY, voxA = -INFINITY;
        #pragma unroll 5
        for (int t = 0; t < TPTS; ++t) {
            float d = b;
            const float4* xr = (const float4*)(&sx2[t][0]);
            #pragma unroll
            for (int q = 0; q < 8; ++q) {
                float4 xv = xr[q];
                d = fmaf(xv.x, w2c[4 * q + 0], d);
                d = fmaf(xv.y, w2c[4 * q + 1], d);
                d = fmaf(xv.z, w2c[4 * q + 2], d);
                d = fmaf(xv.w, w2c[4 * q + 3], d);
            }
            d = fmaxf(d, 0.0f);
            float p = fmaf(d, scale, shift);
            aggAll = fmaxf(aggAll, p);
            voxA = fmaxf(voxA, p * smask[t]);
        }
        float voxB;
        if (nvalid == 0) voxB = 0.0f;
        else if (nvalid < TPTS) voxB = fmaxf(aggAll, 0.0f);
        else voxB = aggAll;
        const int4 c = ((const int4*)coord)[k];
        const int loc = (((c.x * DD + c.y) * HH + c.z) * WW + c.w);
        float* o = out + (size_t)loc * CO;
        atomicAdd(o + v, voxA);
        atomicAdd(o + 64 + v, voxB);
    }
}

extern "C" void kernel_launch(void* const* d_in, const int* in_sizes, int n_in,
                              void* d_out, int out_size, void* d_ws, size_t ws_size,
                              hipStream_t stream) {
    const float* feat = (const float*)d_in[0];
    const float* w1   = (const float*)d_in[1];
    const float* b1   = (const float*)d_in[2];
    const float* g1   = (const float*)d_in[3];
    const float* be1  = (const float*)d_in[4];
    const float* m1   = (const float*)d_in[5];
    const float* v1   = (const float*)d_in[6];
    const float* w2   = (const float*)d_in[7];
    const float* b2   = (const float*)d_in[8];
    const float* g2   = (const float*)d_in[9];
    const float* be2  = (const float*)d_in[10];
    const float* m2   = (const float*)d_in[11];
    const float* v2   = (const float*)d_in[12];
    const int*   coord = (const int*)d_in[13];
    float* out = (float*)d_out;

    const size_t voxB = (size_t)KVOX * CO * sizeof(float);   // 6,144,000 B

    if (ws_size >= voxB) {
        float* vox = (float*)d_ws;
        fused_fill_compute<<<CB, 256, 0, stream>>>(feat, w1, b1, g1, be1, m1, v1,
                                                   w2, b2, g2, be2, m2, v2,
                                                   vox, out);
        scatter_add<<<SB, 256, 0, stream>>>(vox, coord, out);
    } else {
        hipMemsetAsync(d_out, 0, (size_t)out_size * sizeof(float), stream);
        vfe_scatter_atomic<<<KVOX, 64, 0, stream>>>(feat, w1, b1, g1, be1, m1, v1,
                                                    w2, b2, g2, be2, m2, v2, coord, out);
    }
}

// Round 4
// 752.908 us; speedup vs baseline: 1.0561x; 1.0058x over previous
//
#include <hip/hip_runtime.h>

#define KVOX 12000
#define TPTS 35
#define FIN  7
#define DD   10
#define HH   400
#define WW   352
#define CO   128
#define EPSBN 1e-3f
#define NCELL (DD * HH * WW)              // 1,408,000 cells
#define CB    3000                        // fused kernel blocks (4 waves = 4 voxels each)
#define TOTALF4 ((size_t)NCELL * 32)      // 45,056,000 float4s = 720.9 MB
#define SB    1500                        // scatter kernel blocks

static_assert(CB * 4 == KVOX, "grid covers voxels exactly");

// ---- fused: zero-fill `out` + compute voxelwise [KVOX,128] into ws ----
// fill is HBM-store-drain-bound (~115us); compute is LDS-issue work that
// should hide under it. Block parity alternates phase order so the store
// pipe saturates from t=0.
__global__ __launch_bounds__(256) void fused_fill_compute(
    const float* __restrict__ feat,
    const float* __restrict__ w1, const float* __restrict__ b1,
    const float* __restrict__ g1, const float* __restrict__ be1,
    const float* __restrict__ m1, const float* __restrict__ v1,
    const float* __restrict__ w2, const float* __restrict__ b2,
    const float* __restrict__ g2, const float* __restrict__ be2,
    const float* __restrict__ m2, const float* __restrict__ v2,
    float* __restrict__ vox,          // [KVOX, 128]
    float* __restrict__ out)
{
    const int tid  = threadIdx.x;
    const int wv   = tid >> 6;        // wave in block: 0..3
    const int lane = tid & 63;
    const int k    = blockIdx.x * 4 + wv;

    __shared__ __align__(16) float sxp[4][TPTS][8];    // padded point features
    __shared__ __align__(16) float spwm[4][TPTS][16];  // masked stage-1 pointwise
    __shared__ __align__(16) float sagg[4][16];        // stage-1 aggregate (unmasked)

    const bool fillFirst = (blockIdx.x & 1);

    auto do_fill = [&]() {
        const float4 z = make_float4(0.f, 0.f, 0.f, 0.f);
        float4* o4 = (float4*)out;
        const size_t stride = (size_t)CB * 256;
        for (size_t i = (size_t)blockIdx.x * 256 + tid; i < TOTALF4; i += stride)
            o4[i] = z;
    };

    if (fillFirst) do_fill();

    // ---------------- compute: one wave per voxel ----------------
    const float* fk = feat + (size_t)k * (TPTS * FIN);

    // stage features into LDS, padded rows of 8 (row pad -> b128 reads later)
    for (int i = lane; i < TPTS * FIN; i += 64)
        sxp[wv][i / FIN][i % FIN] = fk[i];
    if (lane < TPTS) sxp[wv][lane][FIN] = 0.0f;

    // mask per point straight from global (L1/L2-hot; avoids LDS conflicts)
    bool pred = false;
    if (lane < TPTS) {
        const float* row = fk + lane * FIN;
        float mx = row[0];
        #pragma unroll
        for (int f = 1; f < FIN; ++f) mx = fmaxf(mx, row[f]);
        pred = (mx != 0.0f);
    }
    const unsigned long long bal = __ballot(pred);   // bit t = mask[t] (wave-uniform)
    const int nvalid = __popcll(bal);
    __syncthreads();

    // stage 1: dense(7->16)+relu+BN on lanes u<16; agg over ALL t; masked store
    if (lane < 16) {
        const int u = lane;
        float w1c[8];
        #pragma unroll
        for (int f = 0; f < FIN; ++f) w1c[f] = w1[f * 16 + u];
        w1c[FIN] = 0.0f;
        const float b     = b1[u];
        const float scale = g1[u] * rsqrtf(v1[u] + EPSBN);
        const float shift = be1[u] - m1[u] * scale;

        float agg = -INFINITY;
        float pw[TPTS];
        #pragma unroll
        for (int t = 0; t < TPTS; ++t) {
            const float4 xa = *(const float4*)&sxp[wv][t][0];  // broadcast b128
            const float4 xb = *(const float4*)&sxp[wv][t][4];
            float d = b;
            d = fmaf(xa.x, w1c[0], d); d = fmaf(xa.y, w1c[1], d);
            d = fmaf(xa.z, w1c[2], d); d = fmaf(xa.w, w1c[3], d);
            d = fmaf(xb.x, w1c[4], d); d = fmaf(xb.y, w1c[5], d);
            d = fmaf(xb.z, w1c[6], d); d = fmaf(xb.w, w1c[7], d);
            d = fmaxf(d, 0.0f);
            const float p = fmaf(d, scale, shift);
            agg = fmaxf(agg, p);
            pw[t] = p;
        }
        sagg[wv][u] = agg;
        #pragma unroll
        for (int t = 0; t < TPTS; ++t) {
            const float mk = ((bal >> t) & 1ULL) ? 1.0f : 0.0f;
            spwm[wv][t][u] = pw[t] * mk;     // banks (t*16+u)%32: conflict-free
        }
    }
    __syncthreads();

    // stage 2: dense(32->64)+relu+BN, channel v per lane, agg-term factorized
    {
        const int v = lane;
        float w2c[32];
        #pragma unroll
        for (int u = 0; u < 32; ++u) w2c[u] = w2[u * 64 + v];
        const float b     = b2[v];
        const float scale = g2[v] * rsqrtf(v2[v] + EPSBN);
        const float shift = be2[v] - m2[v] * scale;

        // aggdot = sum_u agg[u] * w2c[16+u]  (t-independent)
        float aggdot = 0.0f;
        {
            const float4* ar = (const float4*)&sagg[wv][0];
            #pragma unroll
            for (int q = 0; q < 4; ++q) {
                const float4 a = ar[q];
                aggdot = fmaf(a.x, w2c[16 + 4 * q + 0], aggdot);
                aggdot = fmaf(a.y, w2c[16 + 4 * q + 1], aggdot);
                aggdot = fmaf(a.z, w2c[16 + 4 * q + 2], aggdot);
                aggdot = fmaf(a.w, w2c[16 + 4 * q + 3], aggdot);
            }
        }

        float aggAll = -INFINITY;
        float voxA   = -INFINITY;
        #pragma unroll 7
        for (int t = 0; t < TPTS; ++t) {
            const float mk = ((bal >> t) & 1ULL) ? 1.0f : 0.0f;
            const float4* xr = (const float4*)&spwm[wv][t][0];
            float d = fmaf(mk, aggdot, b);
            #pragma unroll
            for (int q = 0; q < 4; ++q) {
                const float4 xv = xr[q];          // broadcast b128
                d = fmaf(xv.x, w2c[4 * q + 0], d);
                d = fmaf(xv.y, w2c[4 * q + 1], d);
                d = fmaf(xv.z, w2c[4 * q + 2], d);
                d = fmaf(xv.w, w2c[4 * q + 3], d);
            }
            d = fmaxf(d, 0.0f);
            const float p = fmaf(d, scale, shift);
            aggAll = fmaxf(aggAll, p);
            voxA   = fmaxf(voxA, p * mk);
        }
        float voxB;
        if (nvalid == 0)          voxB = 0.0f;
        else if (nvalid < TPTS)   voxB = fmaxf(aggAll, 0.0f);
        else                      voxB = aggAll;

        float* vk = vox + (size_t)k * CO;
        vk[v]      = voxA;
        vk[64 + v] = voxB;
    }

    if (!fillFirst) do_fill();
}

// ---- tiny scatter: out[cell(k)*128 + ch] += vox[k*128 + ch] (dups accumulate) ----
__global__ __launch_bounds__(256) void scatter_add(
    const float* __restrict__ vox, const int* __restrict__ coord,
    float* __restrict__ out)
{
    const int stride = SB * 256;
    for (int i = blockIdx.x * 256 + threadIdx.x; i < KVOX * CO; i += stride) {
        const int k  = i >> 7;
        const int ch = i & (CO - 1);
        const int4 c = ((const int4*)coord)[k];
        const int loc = (((c.x * DD + c.y) * HH + c.z) * WW + c.w);
        atomicAdd(out + (size_t)loc * CO + ch, vox[i]);
    }
}

// ---- fallback if ws is too small (R1 path) ----
__global__ __launch_bounds__(64) void vfe_scatter_atomic(
    const float* __restrict__ feat,
    const float* __restrict__ w1, const float* __restrict__ b1,
    const float* __restrict__ g1, const float* __restrict__ be1,
    const float* __restrict__ m1, const float* __restrict__ v1,
    const float* __restrict__ w2, const float* __restrict__ b2,
    const float* __restrict__ g2, const float* __restrict__ be2,
    const float* __restrict__ m2, const float* __restrict__ v2,
    const int* __restrict__ coord,
    float* __restrict__ out)
{
    const int k   = blockIdx.x;
    const int tid = threadIdx.x;
    __shared__ float sx[TPTS][FIN];
    __shared__ float smask[TPTS];
    __shared__ __align__(16) float sx2[TPTS][32];
    const float* fk = feat + (size_t)k * (TPTS * FIN);
    for (int i = tid; i < TPTS * FIN; i += 64) ((float*)sx)[i] = fk[i];
    __syncthreads();
    bool pred = false;
    if (tid < TPTS) {
        float mx = sx[tid][0];
        #pragma unroll
        for (int f = 1; f < FIN; ++f) mx = fmaxf(mx, sx[tid][f]);
        pred = (mx != 0.0f);
        smask[tid] = pred ? 1.0f : 0.0f;
    }
    unsigned long long bal = __ballot(pred);
    const int nvalid = __popcll(bal);
    __syncthreads();
    if (tid < 16) {
        const int u = tid;
        float w1c[FIN];
        #pragma unroll
        for (int f = 0; f < FIN; ++f) w1c[f] = w1[f * 16 + u];
        const float b = b1[u];
        const float scale = g1[u] * rsqrtf(v1[u] + EPSBN);
        const float shift = be1[u] - m1[u] * scale;
        float agg = -INFINITY;
        float pw[TPTS];
        #pragma unroll
        for (int t = 0; t < TPTS; ++t) {
            float d = b;
            #pragma unroll
            for (int f = 0; f < FIN; ++f) d = fmaf(sx[t][f], w1c[f], d);
            d = fmaxf(d, 0.0f);
            float p = fmaf(d, scale, shift);
            agg = fmaxf(agg, p);
            pw[t] = p;
        }
        #pragma unroll
        for (int t = 0; t < TPTS; ++t) {
            const float mk = smask[t];
            sx2[t][u] = pw[t] * mk;
            sx2[t][16 + u] = agg * mk;
        }
    }
    __syncthreads();
    {
        const int v = tid;
        float w2c[32];
        #pragma unroll
        for (int u = 0; u < 32; ++u) w2c[u] = w2[u * 64 + v];
        const float b = b2[v];
        const float scale = g2[v] * rsqrtf(v2[v] + EPSBN);
        const float shift = be2[v] - m2[v] * scale;
        float aggAll = -INFINITY, voxA = -INFINITY;
        #pragma unroll 5
        for (int t = 0; t < TPTS; ++t) {
            float d = b;
            const float4* xr = (const float4*)(&sx2[t][0]);
            #pragma unroll
            for (int q = 0; q < 8; ++q) {
                float4 xv = xr[q];
                d = fmaf(xv.x, w2c[4 * q + 0], d);
                d = fmaf(xv.y, w2c[4 * q + 1], d);
                d = fmaf(xv.z, w2c[4 * q + 2], d);
                d = fmaf(xv.w, w2c[4 * q + 3], d);
            }
            d = fmaxf(d, 0.0f);
            float p = fmaf(d, scale, shift);
            aggAll = fmaxf(aggAll, p);
            voxA = fmaxf(voxA, p * smask[t]);
        }
        float voxB;
        if (nvalid == 0) voxB = 0.0f;
        else if (nvalid < TPTS) voxB = fmaxf(aggAll, 0.0f);
        else voxB = aggAll;
        const int4 c = ((const int4*)coord)[k];
        const int loc = (((c.x * DD + c.y) * HH + c.z) * WW + c.w);
        float* o = out + (size_t)loc * CO;
        atomicAdd(o + v, voxA);
        atomicAdd(o + 64 + v, voxB);
    }
}

extern "C" void kernel_launch(void* const* d_in, const int* in_sizes, int n_in,
                              void* d_out, int out_size, void* d_ws, size_t ws_size,
                              hipStream_t stream) {
    const float* feat = (const float*)d_in[0];
    const float* w1   = (const float*)d_in[1];
    const float* b1   = (const float*)d_in[2];
    const float* g1   = (const float*)d_in[3];
    const float* be1  = (const float*)d_in[4];
    const float* m1   = (const float*)d_in[5];
    const float* v1   = (const float*)d_in[6];
    const float* w2   = (const float*)d_in[7];
    const float* b2   = (const float*)d_in[8];
    const float* g2   = (const float*)d_in[9];
    const float* be2  = (const float*)d_in[10];
    const float* m2   = (const float*)d_in[11];
    const float* v2   = (const float*)d_in[12];
    const int*   coord = (const int*)d_in[13];
    float* out = (float*)d_out;

    const size_t voxB = (size_t)KVOX * CO * sizeof(float);   // 6,144,000 B

    if (ws_size >= voxB) {
        float* vox = (float*)d_ws;
        fused_fill_compute<<<CB, 256, 0, stream>>>(feat, w1, b1, g1, be1, m1, v1,
                                                   w2, b2, g2, be2, m2, v2,
                                                   vox, out);
        scatter_add<<<SB, 256, 0, stream>>>(vox, coord, out);
    } else {
        hipMemsetAsync(d_out, 0, (size_t)out_size * sizeof(float), stream);
        vfe_scatter_atomic<<<KVOX, 64, 0, stream>>>(feat, w1, b1, g1, be1, m1, v1,
                                                    w2, b2, g2, be2, m2, v2, coord, out);
    }
}